// Round 5
// baseline (322.911 us; speedup 1.0000x reference)
//
#include <hip/hip_runtime.h>

// ---------------------------------------------------------------------------
// EfficientCrossAttention on MI355X (gfx950)
// B=4 T=4096 D=1024 ; N=2048 L=768 ; H=16 dh=64
//
// R10: R9 + attn_partial/attn_finalize merged into ONE attn_kernel:
//      64 blocks (bh) x 512 thr (2 groups x 4 waves, each reduces 1024 n),
//      coalesced K/V loads (8 lanes = one 128B head-slice), register
//      prefetch of next chunk, MFMA compute (R9-verified fragment layout),
//      cross-group f32 reduction + transpose in LDS, coalesced bf16
//      attnT[l][d] writes. Kills the part round-trip and one launch
//      (~10us/launch per R5->R9 calibration). GEMMs/prep unchanged (R5
//      structure is the verified local optimum; R6-R8 structural attempts
//      all regressed).
//
// Fragment-major layout for X[M][K]: chunk (rt=row>>4, kb=k>>5) of 512 elems;
// within chunk: elem (p=(k>>3)&3, ri=row&15, ko=k&7) at p*128 + ri*8 + ko.
// A wave reading rows rt*16..+15, k-piece p=lane>>4 reads chunk + lane*16B.
// ---------------------------------------------------------------------------

#define DEV __device__ __forceinline__

typedef unsigned short bf16_t;
typedef __attribute__((ext_vector_type(8))) __bf16 bf16x8;
typedef __attribute__((ext_vector_type(8))) unsigned short ushort8;
typedef __attribute__((ext_vector_type(4))) float f32x4;

DEV unsigned short f2bf(float f) {            // RNE float->bf16 (finite inputs)
  unsigned int u = __float_as_uint(f);
  unsigned int r = 0x7FFFu + ((u >> 16) & 1u);
  return (unsigned short)((u + r) >> 16);
}
DEV float bf2f(unsigned short u) { return __uint_as_float(((unsigned int)u) << 16); }

DEV void gld16(const void* g, void* l) {      // async global->LDS, 16B/lane
  __builtin_amdgcn_global_load_lds((__attribute__((address_space(1))) void*)g,
                                   (__attribute__((address_space(3))) void*)l, 16, 0, 0);
}

// ---------------------------------------------------------------------------
// prep_kernel: merged wprep (blocks [0,3584)), ln1 ([3584,4608)),
// ln2 ([4608,5120)). All independent, memory-bound; one launch kills two
// inter-kernel gaps. Shared LDS buffer = max of the three needs (33KB).
// ---------------------------------------------------------------------------
__global__ __launch_bounds__(256) void prep_kernel(
    const float* __restrict__ Wq, const float* __restrict__ Wk,
    const float* __restrict__ Wv, const float* __restrict__ Wh,
    bf16_t* __restrict__ Wqf, bf16_t* __restrict__ Wkf,
    bf16_t* __restrict__ Wvf, bf16_t* __restrict__ Whf,
    const float* __restrict__ x1, const float* __restrict__ g1,
    const float* __restrict__ b1, bf16_t* __restrict__ nx1f,
    bf16_t* __restrict__ x1f,
    const float* __restrict__ x2, const float* __restrict__ g2,
    const float* __restrict__ b2, bf16_t* __restrict__ nx2f) {
  __shared__ __align__(16) char smem[16 * 1032 * 2];   // 33024 B
  __shared__ float murs[16][2];
  int blk = blockIdx.x, tid = threadIdx.x;

  if (blk < 3584) {
    // ---------------- wprep: W (K x 1024 f32) -> fragment-major bf16 -------
    int t = blk;
    const float* src; bf16_t* dst; int KB;
    if (t < 1024)      { src = Wq; dst = Wqf; KB = 32; }
    else if (t < 1792) { src = Wk; dst = Wkf; KB = 24; t -= 1024; }
    else if (t < 2560) { src = Wv; dst = Wvf; KB = 24; t -= 1792; }
    else               { src = Wh; dst = Whf; KB = 32; t -= 2560; }
    int tk = t >> 5, tn = t & 31;
    float (*tile)[33] = (float(*)[33])smem;
    int tx = tid & 31, ty = tid >> 5;
#pragma unroll
    for (int i = 0; i < 4; ++i) {
      int r = ty + i * 8;
      tile[r][tx] = src[(size_t)(tk * 32 + r) * 1024 + tn * 32 + tx];
    }
    __syncthreads();
    if (tid < 128) {
      int rt = tid >> 6, p = (tid >> 4) & 3, ri = tid & 15;
      ushort8 v;
#pragma unroll
      for (int ko = 0; ko < 8; ++ko)
        v[ko] = f2bf(tile[p * 8 + ko][rt * 16 + ri]);
      size_t off = ((size_t)(tn * 2 + rt) * KB + tk) * 512 + p * 128 + ri * 8;
      *(ushort8*)&dst[off] = v;
    }
    return;
  }

  if (blk < 4608) {
    // ---------------- ln1: rows of 1024 -> nx1f + x1f fragment-major -------
    bf16_t* stash = (bf16_t*)smem;                  // rows padded to 1032
    int rt = blk - 3584;
    {
      int rowl = tid >> 4, ci = tid & 15;
      size_t base = ((size_t)rt * 16 + rowl) * 1024;
      float s = 0.f, s2 = 0.f;
#pragma unroll
      for (int j = 0; j < 16; ++j) {
        int k0 = ci * 4 + j * 64;
        float4 f = *(const float4*)&x1[base + k0];
        s += f.x + f.y + f.z + f.w;
        s2 += f.x * f.x + f.y * f.y + f.z * f.z + f.w * f.w;
        ushort4 u;
        u.x = f2bf(f.x); u.y = f2bf(f.y); u.z = f2bf(f.z); u.w = f2bf(f.w);
        *(ushort4*)&stash[rowl * 1032 + k0] = u;
      }
#pragma unroll
      for (int off = 1; off < 16; off <<= 1) {
        s  += __shfl_xor(s, off);
        s2 += __shfl_xor(s2, off);
      }
      if (ci == 0) {
        float mu = s * (1.0f / 1024.0f);
        float var = s2 * (1.0f / 1024.0f) - mu * mu;
        murs[rowl][0] = mu;
        murs[rowl][1] = rsqrtf(var + 1e-5f);
      }
    }
    __syncthreads();
    {
      int ri = tid & 15, pg = tid >> 4;
      float mu = murs[ri][0], rs = murs[ri][1];
#pragma unroll
      for (int t = 0; t < 8; ++t) {
        int P = pg * 8 + t;                          // piece 0..127
        ushort8 raw = *(const ushort8*)&stash[ri * 1032 + P * 8];
        float4 ga = *(const float4*)&g1[P * 8], gb = *(const float4*)&g1[P * 8 + 4];
        float4 ba = *(const float4*)&b1[P * 8], bb = *(const float4*)&b1[P * 8 + 4];
        float gv[8] = {ga.x, ga.y, ga.z, ga.w, gb.x, gb.y, gb.z, gb.w};
        float bv[8] = {ba.x, ba.y, ba.z, ba.w, bb.x, bb.y, bb.z, bb.w};
        ushort8 nv;
#pragma unroll
        for (int ko = 0; ko < 8; ++ko)
          nv[ko] = f2bf((bf2f(raw[ko]) - mu) * rs * gv[ko] + bv[ko]);
        size_t off = ((size_t)rt * 32 + (P >> 2)) * 512 + (P & 3) * 128 + ri * 8;
        *(ushort8*)&nx1f[off] = nv;
        *(ushort8*)&x1f[off] = raw;
      }
    }
    return;
  }

  {
    // ---------------- ln2: rows of 768 -> nx2f fragment-major --------------
    bf16_t* stash = (bf16_t*)smem;                  // rows padded to 776
    int rt = blk - 4608;
    {
      int rowl = tid >> 4, ci = tid & 15;
      size_t base = ((size_t)rt * 16 + rowl) * 768;
      float s = 0.f, s2 = 0.f;
#pragma unroll
      for (int j = 0; j < 12; ++j) {
        int k0 = ci * 4 + j * 64;
        float4 f = *(const float4*)&x2[base + k0];
        s += f.x + f.y + f.z + f.w;
        s2 += f.x * f.x + f.y * f.y + f.z * f.z + f.w * f.w;
        ushort4 u;
        u.x = f2bf(f.x); u.y = f2bf(f.y); u.z = f2bf(f.z); u.w = f2bf(f.w);
        *(ushort4*)&stash[rowl * 776 + k0] = u;
      }
#pragma unroll
      for (int off = 1; off < 16; off <<= 1) {
        s  += __shfl_xor(s, off);
        s2 += __shfl_xor(s2, off);
      }
      if (ci == 0) {
        float mu = s * (1.0f / 768.0f);
        float var = s2 * (1.0f / 768.0f) - mu * mu;
        murs[rowl][0] = mu;
        murs[rowl][1] = rsqrtf(var + 1e-5f);
      }
    }
    __syncthreads();
    {
      int ri = tid & 15, pg = tid >> 4;
      float mu = murs[ri][0], rs = murs[ri][1];
#pragma unroll
      for (int t = 0; t < 6; ++t) {
        int P = pg * 6 + t;                          // piece 0..95
        ushort8 raw = *(const ushort8*)&stash[ri * 776 + P * 8];
        float4 ga = *(const float4*)&g2[P * 8], gb = *(const float4*)&g2[P * 8 + 4];
        float4 ba = *(const float4*)&b2[P * 8], bb = *(const float4*)&b2[P * 8 + 4];
        float gv[8] = {ga.x, ga.y, ga.z, ga.w, gb.x, gb.y, gb.z, gb.w};
        float bv[8] = {ba.x, ba.y, ba.z, ba.w, bb.x, bb.y, bb.z, bb.w};
        ushort8 nv;
#pragma unroll
        for (int ko = 0; ko < 8; ++ko)
          nv[ko] = f2bf((bf2f(raw[ko]) - mu) * rs * gv[ko] + bv[ko]);
        size_t off = ((size_t)rt * 24 + (P >> 2)) * 512 + (P & 3) * 128 + ri * 8;
        *(ushort8*)&nx2f[off] = nv;
      }
    }
  }
}

// ---------------------------------------------------------------------------
// Merged q/k/v GEMM (R5 structure, verified). Block 128x256, waves 2x2 of
// 64x128, 16x16x32 bf16 MFMA. A-frags direct from fragment-major global;
// B staged fragment-major into dbuf LDS; raw vmcnt(8)+barrier pipeline.
//   [0,512):    q = softmax(nx1 @ Wq + bq), nk=32, bm=id&127
//   [512,768):  k = softmax(nx2 @ Wk + bk), nk=24, bm=id&63
//   [768,1024): v =          nx2 @ Wv + bv
// id%8 == bm%8 -> A-tile sharers on one XCD.
// ---------------------------------------------------------------------------
__global__ __launch_bounds__(256, 2) void gemm_qkv_kernel(
    const bf16_t* __restrict__ nx1f, const bf16_t* __restrict__ Wqf,
    const float* __restrict__ bq, bf16_t* __restrict__ qout,
    const bf16_t* __restrict__ nx2f, const bf16_t* __restrict__ Wkf,
    const float* __restrict__ bk, bf16_t* __restrict__ kout,
    const bf16_t* __restrict__ Wvf, const float* __restrict__ bv,
    bf16_t* __restrict__ vout) {
  __shared__ bf16_t Bs[2 * 16 * 512];
  int id = blockIdx.x;
  const bf16_t *A, *BT; const float* bias; bf16_t* out;
  int nk, bm, bn, do_softmax;
  if (id < 512) {
    A = nx1f; BT = Wqf; bias = bq; out = qout; nk = 32;
    bm = id & 127; bn = id >> 7; do_softmax = 1;
  } else if (id < 768) {
    id -= 512; A = nx2f; BT = Wkf; bias = bk; out = kout; nk = 24;
    bm = id & 63; bn = id >> 6; do_softmax = 1;
  } else {
    id -= 768; A = nx2f; BT = Wvf; bias = bv; out = vout; nk = 24;
    bm = id & 63; bn = id >> 6; do_softmax = 0;
  }
  int tid = threadIdx.x, lane = tid & 63, wid = tid >> 6;
  int wm = wid & 1, wn = wid >> 1;

  const bf16_t* ap[4];
#pragma unroll
  for (int mi = 0; mi < 4; ++mi)
    ap[mi] = A + ((size_t)(bm * 8 + wm * 4 + mi) * nk) * 512 + lane * 8;
  const bf16_t* sp[4];
#pragma unroll
  for (int i = 0; i < 4; ++i)
    sp[i] = BT + ((size_t)(bn * 16 + wid * 4 + i) * nk) * 512 + lane * 8;

  f32x4 acc[4][8];
#pragma unroll
  for (int i = 0; i < 4; ++i)
#pragma unroll
    for (int j = 0; j < 8; ++j) acc[i][j] = {0.f, 0.f, 0.f, 0.f};

  bf16x8 acur[4], anxt[4];
  // prologue: stage kt=0 into buf0, load A-frags kt=0
#pragma unroll
  for (int i = 0; i < 4; ++i)
    gld16(sp[i], (void*)&Bs[(wid * 4 + i) * 512 + lane * 8]);
#pragma unroll
  for (int mi = 0; mi < 4; ++mi) acur[mi] = *(const bf16x8*)ap[mi];

  for (int kt = 0; kt < nk; ++kt) {
    int cb = kt & 1;
    if (kt + 1 < nk) {
      int nb = cb ^ 1;
#pragma unroll
      for (int i = 0; i < 4; ++i)
        gld16(sp[i] + (kt + 1) * 512, (void*)&Bs[nb * 8192 + (wid * 4 + i) * 512 + lane * 8]);
#pragma unroll
      for (int mi = 0; mi < 4; ++mi) anxt[mi] = *(const bf16x8*)(ap[mi] + (kt + 1) * 512);
      // wait only the PREVIOUS iter's 8 vmem (stage kt + A kt); the 8 just
      // issued stay in flight across the barrier.
      asm volatile("s_waitcnt vmcnt(8)\n\ts_barrier" ::: "memory");
    } else {
      asm volatile("s_waitcnt vmcnt(0)\n\ts_barrier" ::: "memory");
    }
    bf16x8 bfr[8];
#pragma unroll
    for (int ni = 0; ni < 8; ++ni)
      bfr[ni] = *(const bf16x8*)&Bs[cb * 8192 + (wn * 8 + ni) * 512 + lane * 8];
#pragma unroll
    for (int mi = 0; mi < 4; ++mi)
#pragma unroll
      for (int ni = 0; ni < 8; ++ni)
        acc[mi][ni] = __builtin_amdgcn_mfma_f32_16x16x32_bf16(acur[mi], bfr[ni], acc[mi][ni], 0, 0, 0);
    // all waves must finish reading Bs[cb] before anyone stages kt+2 into it
    asm volatile("s_waitcnt lgkmcnt(0)\n\ts_barrier" ::: "memory");
#pragma unroll
    for (int mi = 0; mi < 4; ++mi) acur[mi] = anxt[mi];
  }

  int colg0 = bn * 256 + wn * 128;
  float bvv[8];
#pragma unroll
  for (int ni = 0; ni < 8; ++ni) bvv[ni] = bias[colg0 + ni * 16 + (lane & 15)];
#pragma unroll
  for (int mi = 0; mi < 4; ++mi) {
#pragma unroll
    for (int r = 0; r < 4; ++r) {
      int row = bm * 128 + wm * 64 + mi * 16 + (lane >> 4) * 4 + r;
      float vx[8];
#pragma unroll
      for (int ni = 0; ni < 8; ++ni) vx[ni] = acc[mi][ni][r] + bvv[ni];
      if (do_softmax) {
        // two heads per wave span; logits ~N(0,1): exp w/o max-pass is safe
#pragma unroll
        for (int g = 0; g < 2; ++g) {
          float ssum = 0.f;
#pragma unroll
          for (int j = 0; j < 4; ++j) { vx[g * 4 + j] = __expf(vx[g * 4 + j]); ssum += vx[g * 4 + j]; }
#pragma unroll
          for (int off = 1; off < 16; off <<= 1) ssum += __shfl_xor(ssum, off);
          float inv = 1.0f / ssum;
#pragma unroll
          for (int j = 0; j < 4; ++j) vx[g * 4 + j] *= inv;
        }
      }
#pragma unroll
      for (int ni = 0; ni < 8; ++ni)
        out[(size_t)row * 1024 + colg0 + ni * 16 + (lane & 15)] = f2bf(vx[ni]);
    }
  }
}

// ---------------------------------------------------------------------------
// attn_kernel (R10): one block per (b,h); 512 thr = 2 groups x 4 waves.
// Group g reduces n in [g*1024, (g+1)*1024) over 32 chunks of 32 n:
//   - coalesced loads: 8 lanes cover one n-row's contiguous 128B head-slice
//   - register prefetch of chunk s+1 issued before the compute barrier
//   - MFMA 16x16x32: per chunk, wave computes d-strip x 64 l (4 MFMA)
//     (fragment conventions identical to the verified GEMMs / R9 partial)
// Epilogue: group 0 writes acc into f32 Pt[l][d] (LDS), group 1 adds, then
// all 512 threads emit attnT[bh][l][d] bf16 with coalesced 16B stores.
// Replaces attn_partial + attn_finalize (one fewer launch, no part buffer).
// ---------------------------------------------------------------------------
__global__ __launch_bounds__(512) void attn_kernel(
    const bf16_t* __restrict__ kq, const bf16_t* __restrict__ vq,
    bf16_t* __restrict__ attnT) {
  __shared__ __align__(16) char smem[20480];       // staging 2x10240B; Pt 17408B
  int bh = blockIdx.x;
  int b = bh >> 4, h = bh & 15;
  int tid = threadIdx.x;
  int g = tid >> 8, tl = tid & 255;
  int lane = tid & 63, wid = (tid >> 6) & 3;
  bf16_t* KT = (bf16_t*)(smem + g * 10240);        // [64 d][40] (pad)
  bf16_t* VT = KT + 2560;                          // [64 l][40]
  float* Pt = (float*)smem;                        // [64 l][68] after loop

  int nr = tl >> 3, col = (tl & 7) * 8;            // n-row 0..31, d-piece
  int m = lane & 15, kp = lane >> 4;

  f32x4 acc[4];
#pragma unroll
  for (int ni = 0; ni < 4; ++ni) acc[ni] = {0.f, 0.f, 0.f, 0.f};

  size_t gbase = ((size_t)(b * 2048 + g * 1024 + nr)) * 1024 + h * 64 + col;
  ushort8 ck = *(const ushort8*)&kq[gbase];
  ushort8 cv = *(const ushort8*)&vq[gbase];

  for (int s = 0; s < 32; ++s) {
    if (s) __syncthreads();                        // prev compute done
#pragma unroll
    for (int j = 0; j < 8; ++j) {                  // transpose-scatter to LDS
      KT[(col + j) * 40 + nr] = (bf16_t)ck[j];
      VT[(col + j) * 40 + nr] = (bf16_t)cv[j];
    }
    if (s + 1 < 32) {                              // prefetch next chunk
      size_t go = gbase + (size_t)(s + 1) * 32 * 1024;
      ck = *(const ushort8*)&kq[go];
      cv = *(const ushort8*)&vq[go];
    }
    __syncthreads();                               // staging visible
    bf16x8 af = *(const bf16x8*)&KT[(wid * 16 + m) * 40 + kp * 8];
#pragma unroll
    for (int ni = 0; ni < 4; ++ni) {
      bf16x8 bf = *(const bf16x8*)&VT[(ni * 16 + m) * 40 + kp * 8];
      acc[ni] = __builtin_amdgcn_mfma_f32_16x16x32_bf16(af, bf, acc[ni], 0, 0, 0);
    }
  }
  __syncthreads();                                 // all compute done
  if (g == 0) {
#pragma unroll
    for (int ni = 0; ni < 4; ++ni)
#pragma unroll
      for (int r = 0; r < 4; ++r)
        Pt[(ni * 16 + m) * 68 + wid * 16 + kp * 4 + r] = acc[ni][r];
  }
  __syncthreads();
  if (g == 1) {
#pragma unroll
    for (int ni = 0; ni < 4; ++ni)
#pragma unroll
      for (int r = 0; r < 4; ++r)
        Pt[(ni * 16 + m) * 68 + wid * 16 + kp * 4 + r] += acc[ni][r];
  }
  __syncthreads();
  {
    int l = tid >> 3, d0 = (tid & 7) * 8;
    float4 pa = *(const float4*)&Pt[l * 68 + d0];
    float4 pb = *(const float4*)&Pt[l * 68 + d0 + 4];
    ushort8 o;
    o[0] = f2bf(pa.x); o[1] = f2bf(pa.y); o[2] = f2bf(pa.z); o[3] = f2bf(pa.w);
    o[4] = f2bf(pb.x); o[5] = f2bf(pb.y); o[6] = f2bf(pb.z); o[7] = f2bf(pb.w);
    *(ushort8*)&attnT[((size_t)bh * 64 + l) * 64 + d0] = o;
  }
}

// ---------------------------------------------------------------------------
// Final GEMM: out = x1 @ Wh + bh + q @ blockdiag(attn), fp32 out.
// R5 pipeline (A = x1f fragment-major direct, B = Whf staged dbuf).
// grid (128, 4), bm fast. y-tail: 2 direct K-steps on (qb, attnT).
// ---------------------------------------------------------------------------
__global__ __launch_bounds__(256, 2) void gemm_final_kernel(
    const bf16_t* __restrict__ x1f, const bf16_t* __restrict__ Whf,
    const float* __restrict__ bias, const bf16_t* __restrict__ qb,
    const bf16_t* __restrict__ attnT, float* __restrict__ out) {
  __shared__ bf16_t Bs[2 * 16 * 512];
  const int nk = 32;
  int tid = threadIdx.x;
  int bm = blockIdx.x, bn = blockIdx.y;
  int lane = tid & 63, wid = tid >> 6;
  int wm = wid & 1, wn = wid >> 1;
  int b = bm >> 5;                       // 32 m-tiles per batch
  int klane = (lane >> 4) * 8;

  const bf16_t* ap[4];
#pragma unroll
  for (int mi = 0; mi < 4; ++mi)
    ap[mi] = x1f + ((size_t)(bm * 8 + wm * 4 + mi) * nk) * 512 + lane * 8;
  const bf16_t* sp[4];
#pragma unroll
  for (int i = 0; i < 4; ++i)
    sp[i] = Whf + ((size_t)(bn * 16 + wid * 4 + i) * nk) * 512 + lane * 8;

  f32x4 acc[4][8];
#pragma unroll
  for (int i = 0; i < 4; ++i)
#pragma unroll
    for (int j = 0; j < 8; ++j) acc[i][j] = {0.f, 0.f, 0.f, 0.f};

  bf16x8 acur[4], anxt[4];
#pragma unroll
  for (int i = 0; i < 4; ++i)
    gld16(sp[i], (void*)&Bs[(wid * 4 + i) * 512 + lane * 8]);
#pragma unroll
  for (int mi = 0; mi < 4; ++mi) acur[mi] = *(const bf16x8*)ap[mi];

  for (int kt = 0; kt < nk; ++kt) {
    int cb = kt & 1;
    if (kt + 1 < nk) {
      int nb = cb ^ 1;
#pragma unroll
      for (int i = 0; i < 4; ++i)
        gld16(sp[i] + (kt + 1) * 512, (void*)&Bs[nb * 8192 + (wid * 4 + i) * 512 + lane * 8]);
#pragma unroll
      for (int mi = 0; mi < 4; ++mi) anxt[mi] = *(const bf16x8*)(ap[mi] + (kt + 1) * 512);
      asm volatile("s_waitcnt vmcnt(8)\n\ts_barrier" ::: "memory");
    } else {
      asm volatile("s_waitcnt vmcnt(0)\n\ts_barrier" ::: "memory");
    }
    bf16x8 bfr[8];
#pragma unroll
    for (int ni = 0; ni < 8; ++ni)
      bfr[ni] = *(const bf16x8*)&Bs[cb * 8192 + (wn * 8 + ni) * 512 + lane * 8];
#pragma unroll
    for (int mi = 0; mi < 4; ++mi)
#pragma unroll
      for (int ni = 0; ni < 8; ++ni)
        acc[mi][ni] = __builtin_amdgcn_mfma_f32_16x16x32_bf16(acur[mi], bfr[ni], acc[mi][ni], 0, 0, 0);
    asm volatile("s_waitcnt lgkmcnt(0)\n\ts_barrier" ::: "memory");
#pragma unroll
    for (int mi = 0; mi < 4; ++mi) acur[mi] = anxt[mi];
  }

  // --- y tail: 2 K-steps on (q, attnT). Wave cols = heads h0, h0+1. ---
  {
    int h0 = bn * 4 + wn * 2;
#pragma unroll
    for (int k2 = 0; k2 < 2; ++k2) {
      bf16x8 aq[2][4], bt[8];
#pragma unroll
      for (int g = 0; g < 2; ++g)
#pragma unroll
        for (int mi = 0; mi < 4; ++mi)
          aq[g][mi] = *(const bf16x8*)(qb
              + (size_t)(bm * 128 + wm * 64 + mi * 16 + (lane & 15)) * 1024
              + (h0 + g) * 64 + k2 * 32 + klane);
#pragma unroll
      for (int ni = 0; ni < 8; ++ni)
        bt[ni] = *(const bf16x8*)(attnT
            + ((size_t)(b * 16 + h0 + (ni >> 2)) * 64 + (ni & 3) * 16 + (lane & 15)) * 64
            + k2 * 32 + klane);
#pragma unroll
      for (int mi = 0; mi < 4; ++mi)
#pragma unroll
        for (int ni = 0; ni < 8; ++ni)
          acc[mi][ni] = __builtin_amdgcn_mfma_f32_16x16x32_bf16(aq[ni >> 2][mi], bt[ni], acc[mi][ni], 0, 0, 0);
    }
  }

  int colg0 = bn * 256 + wn * 128;
  float bvv[8];
#pragma unroll
  for (int ni = 0; ni < 8; ++ni) bvv[ni] = bias[colg0 + ni * 16 + (lane & 15)];
#pragma unroll
  for (int mi = 0; mi < 4; ++mi)
#pragma unroll
    for (int r = 0; r < 4; ++r) {
      int row = bm * 128 + wm * 64 + mi * 16 + (lane >> 4) * 4 + r;
#pragma unroll
      for (int ni = 0; ni < 8; ++ni)
        out[(size_t)row * 1024 + colg0 + ni * 16 + (lane & 15)] = acc[mi][ni][r] + bvv[ni];
    }
}

// ---------------------------------------------------------------------------
extern "C" void kernel_launch(void* const* d_in, const int* in_sizes, int n_in,
                              void* d_out, int out_size, void* d_ws, size_t ws_size,
                              hipStream_t stream) {
  const float* x1 = (const float*)d_in[0];
  const float* x2 = (const float*)d_in[1];
  const float* Wq = (const float*)d_in[2];
  const float* bq = (const float*)d_in[3];
  const float* Wk = (const float*)d_in[4];
  const float* bk = (const float*)d_in[5];
  const float* Wv = (const float*)d_in[6];
  const float* bv = (const float*)d_in[7];
  const float* Wh = (const float*)d_in[8];
  const float* bh = (const float*)d_in[9];
  const float* g1 = (const float*)d_in[10];
  const float* b1 = (const float*)d_in[11];
  const float* g2 = (const float*)d_in[12];
  const float* b2 = (const float*)d_in[13];
  float* out = (float*)d_out;

  char* w = (char*)d_ws;
  bf16_t* nx1f = (bf16_t*)w; w += (size_t)16384 * 1024 * 2;
  bf16_t* x1f  = (bf16_t*)w; w += (size_t)16384 * 1024 * 2;
  bf16_t* nx2f = (bf16_t*)w; w += (size_t)8192 * 768 * 2;
  bf16_t* Wqf  = (bf16_t*)w; w += (size_t)1024 * 1024 * 2;
  bf16_t* Wkf  = (bf16_t*)w; w += (size_t)1024 * 768 * 2;
  bf16_t* Wvf  = (bf16_t*)w; w += (size_t)1024 * 768 * 2;
  bf16_t* Whf  = (bf16_t*)w; w += (size_t)1024 * 1024 * 2;
  bf16_t* qb   = (bf16_t*)w; w += (size_t)16384 * 1024 * 2;
  bf16_t* kbuf = (bf16_t*)w; w += (size_t)8192 * 1024 * 2;
  bf16_t* vbuf = (bf16_t*)w; w += (size_t)8192 * 1024 * 2;
  bf16_t* attnT = (bf16_t*)w; w += (size_t)64 * 64 * 64 * 2;

  prep_kernel<<<dim3(5120), dim3(256), 0, stream>>>(
      Wq, Wk, Wv, Wh, Wqf, Wkf, Wvf, Whf,
      x1, g1, b1, nx1f, x1f, x2, g2, b2, nx2f);
  gemm_qkv_kernel<<<dim3(1024), dim3(256), 0, stream>>>(
      nx1f, Wqf, bq, qb, nx2f, Wkf, bk, kbuf, Wvf, bv, vbuf);
  attn_kernel<<<dim3(64), dim3(512), 0, stream>>>(kbuf, vbuf, attnT);
  gemm_final_kernel<<<dim3(128, 4), dim3(256), 0, stream>>>(x1f, Whf, bh, qb, attnT, out);
}